// Round 1
// baseline (6179.827 us; speedup 1.0000x reference)
//
#include <hip/hip_runtime.h>
#include <hip/hip_bf16.h>

// LSTM: B=256, T=512, I=64, H=256. Weights-stationary persistent scan.
// 16 WGs x 1024 threads. Wave w owns hidden slice j in [16w,16w+16) for a
// 16-row batch chunk; W-fragments live in registers for the whole scan.

#define B_TOT 256
#define T_SEQ 512
#define NIN   64
#define HID   256
#define CHUNK 16          // batch rows per WG
#define ROWB  768         // padded LDS row stride in bytes (320 f16 = 640B data)
#define NKK   10          // K = 320 = 10 * 32

typedef _Float16 half8 __attribute__((ext_vector_type(8)));
typedef float    f32x4 __attribute__((ext_vector_type(4)));

__device__ __forceinline__ float fast_rcp(float x) { return __builtin_amdgcn_rcpf(x); }
__device__ __forceinline__ float sigf(float v)     { return fast_rcp(1.0f + __expf(-v)); }
// tanh(x) = 1 - 2/(e^{2x}+1); stable for large |x| (inf -> 1, 0 -> -1)
__device__ __forceinline__ float tanhf_fast(float v){ return 1.0f - 2.0f*fast_rcp(__expf(2.0f*v) + 1.0f); }

__device__ __forceinline__ unsigned short f2h_bits(float f){
    _Float16 h = (_Float16)f;
    return __builtin_bit_cast(unsigned short, h);
}

__global__ void __launch_bounds__(1024, 4)
lstm_scan(const float* __restrict__ x,
          const float* __restrict__ Wih,
          const float* __restrict__ Whh,
          const float* __restrict__ bih,
          const float* __restrict__ bhh,
          const float* __restrict__ Wfc,
          const float* __restrict__ bfc,
          float* __restrict__ out)
{
    // double-buffered activation tile: [16 rows][320 f16] per buffer, XOR-swizzled
    __shared__ __align__(16) char actmem[2*CHUNK*ROWB];
    __shared__ float red[CHUNK][HID + 1];   // +1 pad: conflict-free final reduce

    const int tid  = threadIdx.x;
    const int w    = tid >> 6;      // wave id 0..15 == hidden slice / x batch row
    const int lane = tid & 63;
    const int lr   = lane & 15;     // A row (batch-local) / B col (gate col)
    const int kg   = lane >> 4;     // k-group 0..3
    const int jcol = w*16 + lr;     // this lane's hidden unit j
    const int cb   = blockIdx.x * CHUNK;

    // ---- preload W fragments into registers (B-operand layout) ----
    // wv[g][kk] lane l: W'[n = g*256 + jcol][k = kk*32 + kg*8 + jj], jj=0..7
    half8 wv[4][NKK];
    float biasv[4];
    #pragma unroll
    for (int g = 0; g < 4; ++g) {
        const int n = g*HID + jcol;
        biasv[g] = bih[n] + bhh[n];
        #pragma unroll
        for (int kk = 0; kk < 2; ++kk) {        // k 0..63 -> W_ih
            #pragma unroll
            for (int jj = 0; jj < 8; ++jj) {
                int k = kk*32 + kg*8 + jj;
                wv[g][kk][jj] = (_Float16)Wih[n*NIN + k];
            }
        }
        #pragma unroll
        for (int kk = 2; kk < NKK; ++kk) {      // k 64..319 -> W_hh
            #pragma unroll
            for (int jj = 0; jj < 8; ++jj) {
                int k = kk*32 + kg*8 + jj - NIN;
                wv[g][kk][jj] = (_Float16)Whh[n*HID + k];
            }
        }
    }

    // ---- zero both act buffers (h_0 = 0) ----
    for (int idx = tid; idx < 2*CHUNK*ROWB/4; idx += 1024)
        ((int*)actmem)[idx] = 0;
    __syncthreads();

    // x pointer: wave w loads batch row cb+w, element = lane (coalesced 256B/wave)
    const float* xp = x + (size_t)(cb + w)*T_SEQ*NIN + lane;
    // write x_0 into buffer 0 (col = lane, row = w), swizzled
    *(unsigned short*)(actmem + w*ROWB + ((lane*2) ^ (w << 4))) = f2h_bits(xp[0]);
    __syncthreads();

    float cst[4]   = {0.f, 0.f, 0.f, 0.f};   // cell state, 4 batch rows per lane
    float hlast[4] = {0.f, 0.f, 0.f, 0.f};

    int cur = 0;
    for (int t = 0; t < T_SEQ; ++t) {
        // prefetch x_{t+1} (consumed at the write phase below)
        float xv = xp[(size_t)(t < T_SEQ-1 ? t+1 : T_SEQ-1)*NIN];

        // A-fragments: af[kk] lane l = Act[row = lr][k = kk*32 + kg*8 + jj]
        const char* rbuf = actmem + cur*(CHUNK*ROWB);
        half8 af[NKK];
        #pragma unroll
        for (int kk = 0; kk < NKK; ++kk) {
            int off = (kk*64 + kg*16) ^ (lr << 4);
            af[kk] = *(const half8*)(rbuf + lr*ROWB + off);
        }

        // gates = Act @ W'^T + bias : 4 gate blocks x 10 k-steps
        f32x4 acc[4];
        #pragma unroll
        for (int g = 0; g < 4; ++g) {
            f32x4 a = {biasv[g], biasv[g], biasv[g], biasv[g]};
            #pragma unroll
            for (int kk = 0; kk < NKK; ++kk)
                a = __builtin_amdgcn_mfma_f32_16x16x32_f16(af[kk], wv[g][kk], a, 0, 0, 0);
            acc[g] = a;
        }

        // elementwise LSTM cell; write h_{t+1} (and x_{t+1}) into the other buffer
        char* nbuf = actmem + (cur ^ 1)*(CHUNK*ROWB);
        #pragma unroll
        for (int r = 0; r < 4; ++r) {
            float iv = sigf(acc[0][r]);
            float fv = sigf(acc[1][r]);
            float gv = tanhf_fast(acc[2][r]);
            float ov = sigf(acc[3][r]);
            float cc = fv*cst[r] + iv*gv;
            cst[r] = cc;
            float hv = ov*tanhf_fast(cc);
            hlast[r] = hv;
            int row = kg*4 + r;                       // D row = batch-local row
            int off = ((NIN + jcol)*2) ^ (row << 4);  // h lives at col 64+j
            *(unsigned short*)(nbuf + row*ROWB + off) = f2h_bits(hv);
        }
        *(unsigned short*)(nbuf + w*ROWB + ((lane*2) ^ (w << 4))) = f2h_bits(xv);

        __syncthreads();
        cur ^= 1;
    }

    // ---- final FC: out[b] = sum_j W_fc[j]*h[b][j] + b_fc ----
    {
        float wf = Wfc[jcol];
        #pragma unroll
        for (int r = 0; r < 4; ++r)
            red[kg*4 + r][jcol] = hlast[r]*wf;
    }
    __syncthreads();
    if (tid < CHUNK) {
        float s = bfc[0];
        for (int j = 0; j < HID; ++j) s += red[tid][j];
        out[cb + tid] = s;
    }
}

extern "C" void kernel_launch(void* const* d_in, const int* in_sizes, int n_in,
                              void* d_out, int out_size, void* d_ws, size_t ws_size,
                              hipStream_t stream)
{
    const float* x   = (const float*)d_in[0];
    const float* Wih = (const float*)d_in[1];
    const float* Whh = (const float*)d_in[2];
    const float* bih = (const float*)d_in[3];
    const float* bhh = (const float*)d_in[4];
    const float* Wfc = (const float*)d_in[5];
    const float* bfc = (const float*)d_in[6];
    float* out = (float*)d_out;

    lstm_scan<<<B_TOT/CHUNK, 1024, 0, stream>>>(x, Wih, Whh, bih, bhh, Wfc, bfc, out);
}

// Round 2
// 4960.905 us; speedup vs baseline: 1.2457x; 1.2457x over previous
//
#include <hip/hip_runtime.h>
#include <hip/hip_bf16.h>

// LSTM B=256,T=512,I=64,H=256. 64 WGs = 16 batch-chunks x 4 hidden-slices.
// Each WG: 16 waves, owns 256 gate rows (4 gates x 64 j) -> 40 weight VGPRs/thread.
// Per-step 4-WG h all-gather via device-scope flags in d_ws.

#define B_TOT 256
#define T_SEQ 512
#define NIN   64
#define HID   256
#define CHUNK 16
#define NJW   4
#define JSL   (HID/NJW)     // 64
#define ROWB  768           // LDS act row stride bytes (320 f16 = 640B data)
#define NKK   10            // K = 320 = 10*32

typedef _Float16 half8 __attribute__((ext_vector_type(8)));
typedef float    f32x4 __attribute__((ext_vector_type(4)));

__device__ __forceinline__ float fast_rcp(float x) { return __builtin_amdgcn_rcpf(x); }
__device__ __forceinline__ float sigf(float v)     { return fast_rcp(1.0f + __expf(-v)); }
__device__ __forceinline__ float tanhf_fast(float v){ return 1.0f - 2.0f*fast_rcp(__expf(2.0f*v) + 1.0f); }
__device__ __forceinline__ unsigned short f2h_bits(float f){
    _Float16 h = (_Float16)f;
    return __builtin_bit_cast(unsigned short, h);
}

__global__ void __launch_bounds__(1024, 4)
lstm_scan(const float* __restrict__ x,
          const float* __restrict__ Wih,
          const float* __restrict__ Whh,
          const float* __restrict__ bih,
          const float* __restrict__ bhh,
          const float* __restrict__ Wfc,
          const float* __restrict__ bfc,
          float* __restrict__ out,
          unsigned short* __restrict__ hbuf,   // [2][256][256] f16
          unsigned int* __restrict__ flags)    // [64]
{
    __shared__ __align__(16) char act[CHUNK*ROWB];     // [16 rows][320 f16] swizzled
    __shared__ float gl[CHUNK][4*JSL + 1];             // gate pre-activations, stride 257

    const int tid   = threadIdx.x;
    const int w     = tid >> 6;        // wave id = batch-local row for cell phase
    const int lane  = tid & 63;
    const int lr    = lane & 15;
    const int kg    = lane >> 4;
    const int chunk = blockIdx.x & 15; // partners share (bid mod 16) -> same XCD residue
    const int jw    = blockIdx.x >> 4;

    // this wave's 16 gate rows: n = gg*256 + jw*64 + (w&3)*16 + lr  (lane col = lr)
    const int gg = w >> 2;
    const int n  = gg*HID + jw*JSL + (w & 3)*16 + lr;

    // ---- register-resident weight fragments (B operand), 40 VGPRs ----
    half8 wv[NKK];
    const float bias = bih[n] + bhh[n];
    #pragma unroll
    for (int kk = 0; kk < 2; ++kk) {
        #pragma unroll
        for (int jj = 0; jj < 8; ++jj)
            wv[kk][jj] = (_Float16)Wih[n*NIN + kk*32 + kg*8 + jj];
    }
    #pragma unroll
    for (int kk = 2; kk < NKK; ++kk) {
        #pragma unroll
        for (int jj = 0; jj < 8; ++jj)
            wv[kk][jj] = (_Float16)Whh[n*HID + kk*32 + kg*8 + jj - NIN];
    }

    // ---- init act: h=0, x_0 ----
    for (int i = tid; i < CHUNK*ROWB/4; i += 1024) ((int*)act)[i] = 0;
    __syncthreads();
    {
        float x0 = x[((chunk*CHUNK + w)*T_SEQ + 0)*NIN + lane];
        *(unsigned short*)(act + w*ROWB + ((lane*2) ^ (w << 4))) = f2h_bits(x0);
    }
    __syncthreads();

    float cst = 0.f;       // cell state for (batch row w, j = jw*64+lane)
    float hlast = 0.f;

    for (int t = 0; t < T_SEQ; ++t) {
        // prefetch x_{t+1} for row w, col lane (coalesced 256B/wave)
        const int tn = (t+1 < T_SEQ) ? t+1 : T_SEQ-1;
        const float xv = x[((chunk*CHUNK + w)*T_SEQ + tn)*NIN + lane];

        // A fragments from act (row lr, swizzled)
        half8 af[NKK];
        #pragma unroll
        for (int kk = 0; kk < NKK; ++kk) {
            const int off = (kk*64 + kg*16) ^ (lr << 4);
            af[kk] = *(const half8*)(act + lr*ROWB + off);
        }
        f32x4 acc = {bias, bias, bias, bias};
        #pragma unroll
        for (int kk = 0; kk < NKK; ++kk)
            acc = __builtin_amdgcn_mfma_f32_16x16x32_f16(af[kk], wv[kk], acc, 0, 0, 0);

        // scatter pre-activations to gl: (row kg*4+r, col w*16+lr)
        #pragma unroll
        for (int r = 0; r < 4; ++r)
            gl[kg*4 + r][w*16 + lr] = acc[r];
        __syncthreads();   // B1: gl ready; act safe to overwrite

        // cell update: this thread owns (row=w, jloc=lane)
        const float iv = sigf(gl[w][          lane]);
        const float fv = sigf(gl[w][  JSL  + lane]);
        const float gv = tanhf_fast(gl[w][2*JSL + lane]);
        const float ov = sigf(gl[w][3*JSL + lane]);
        const float cc = fv*cst + iv*gv;
        cst = cc;
        const float hv = ov*tanhf_fast(cc);
        hlast = hv;
        const unsigned short h16 = f2h_bits(hv);

        // own slice directly into act
        const int mycol = NIN + jw*JSL + lane;
        *(unsigned short*)(act + w*ROWB + ((mycol*2) ^ (w << 4))) = h16;

        // publish to partners
        const int par = (t+1) & 1;
        hbuf[(par*B_TOT + chunk*CHUNK + w)*HID + jw*JSL + lane] = h16;

        __syncthreads();   // B2: all h stores drained (barrier implies vmcnt(0))
        if (tid == 0) {
            __builtin_amdgcn_fence(__ATOMIC_RELEASE, "agent");
            __hip_atomic_store(&flags[blockIdx.x], (unsigned)(t+1),
                               __ATOMIC_RELAXED, __HIP_MEMORY_SCOPE_AGENT);
        }
        if (tid < NJW-1) {
            const int pj = (jw + 1 + tid) & 3;
            while (__hip_atomic_load(&flags[(pj << 4) + chunk],
                                     __ATOMIC_RELAXED, __HIP_MEMORY_SCOPE_AGENT)
                   < (unsigned)(t+1)) { }
        }
        __syncthreads();   // B3: partners' data published
        __builtin_amdgcn_fence(__ATOMIC_ACQUIRE, "agent");   // invalidate L1/L2

        // gather partner h slices into act
        #pragma unroll
        for (int p = 0; p < NJW-1; ++p) {
            const int pj = (jw + 1 + p) & 3;
            const unsigned short hp =
                hbuf[(par*B_TOT + chunk*CHUNK + w)*HID + pj*JSL + lane];
            const int col = NIN + pj*JSL + lane;
            *(unsigned short*)(act + w*ROWB + ((col*2) ^ (w << 4))) = hp;
        }
        if (t < T_SEQ-1)
            *(unsigned short*)(act + w*ROWB + ((lane*2) ^ (w << 4))) = f2h_bits(xv);
        __syncthreads();   // B4: act ready for next step
    }

    // ---- final FC: partial dot over this WG's 64 j, atomicAdd into out ----
    {
        float v = Wfc[jw*JSL + lane] * hlast;
        if (jw == 0 && lane == 0) v += bfc[0];
        #pragma unroll
        for (int off = 32; off; off >>= 1) v += __shfl_down(v, off);
        if (lane == 0) atomicAdd(&out[chunk*CHUNK + w], v);
    }
}

extern "C" void kernel_launch(void* const* d_in, const int* in_sizes, int n_in,
                              void* d_out, int out_size, void* d_ws, size_t ws_size,
                              hipStream_t stream)
{
    const float* x   = (const float*)d_in[0];
    const float* Wih = (const float*)d_in[1];
    const float* Whh = (const float*)d_in[2];
    const float* bih = (const float*)d_in[3];
    const float* bhh = (const float*)d_in[4];
    const float* Wfc = (const float*)d_in[5];
    const float* bfc = (const float*)d_in[6];
    float* out = (float*)d_out;

    unsigned int*   flags = (unsigned int*)d_ws;
    unsigned short* hbuf  = (unsigned short*)((char*)d_ws + 1024);

    hipMemsetAsync(d_ws, 0, 1024, stream);                       // flags = 0
    hipMemsetAsync(d_out, 0, out_size*sizeof(float), stream);    // atomicAdd target
    lstm_scan<<<CHUNK*NJW, 1024, 0, stream>>>(x, Wih, Whh, bih, bhh, Wfc, bfc,
                                              out, hbuf, flags);
}

// Round 3
// 898.143 us; speedup vs baseline: 6.8807x; 5.5235x over previous
//
#include <hip/hip_runtime.h>
#include <hip/hip_bf16.h>

// LSTM B=256,T=512,I=64,H=256. 64 WGs = 16 batch-chunks x 4 hidden-slices.
// Weights register-resident (40 VGPR/thread). Per-step h exchange via
// fence-free tagged-word relaxed agent atomics (tag = timestep in hi16).

#define B_TOT 256
#define T_SEQ 512
#define NIN   64
#define HID   256
#define CHUNK 16
#define NJW   4
#define JSL   (HID/NJW)     // 64
#define ROWB  768           // LDS act row stride bytes (320 f16 = 640B data)
#define NKK   10            // K = 320 = 10*32

typedef _Float16 half8 __attribute__((ext_vector_type(8)));
typedef float    f32x4 __attribute__((ext_vector_type(4)));

__device__ __forceinline__ float fast_rcp(float x) { return __builtin_amdgcn_rcpf(x); }
__device__ __forceinline__ float sigf(float v)     { return fast_rcp(1.0f + __expf(-v)); }
__device__ __forceinline__ float tanhf_fast(float v){ return 1.0f - 2.0f*fast_rcp(__expf(2.0f*v) + 1.0f); }
__device__ __forceinline__ unsigned short f2h_bits(float f){
    _Float16 h = (_Float16)f;
    return __builtin_bit_cast(unsigned short, h);
}

__global__ void __launch_bounds__(1024, 4)
lstm_scan(const float* __restrict__ x,
          const float* __restrict__ Wih,
          const float* __restrict__ Whh,
          const float* __restrict__ bih,
          const float* __restrict__ bhh,
          const float* __restrict__ Wfc,
          const float* __restrict__ bfc,
          float* __restrict__ out,
          unsigned int* __restrict__ hq)   // [2][B_TOT][HID] tagged h words
{
    __shared__ __align__(16) char act[CHUNK*ROWB];     // [16 rows][320 f16] swizzled
    __shared__ float gl[CHUNK][4*JSL + 1];             // gate pre-activations

    const int tid   = threadIdx.x;
    const int w     = tid >> 6;        // wave id = batch-local row for cell/gather
    const int lane  = tid & 63;
    const int lr    = lane & 15;
    const int kg    = lane >> 4;
    const int chunk = blockIdx.x & 15;
    const int jw    = blockIdx.x >> 4;
    const int cb    = chunk*CHUNK;

    // this wave's 16 gate rows: n = gg*256 + jw*64 + (w&3)*16 + lr
    const int gg = w >> 2;
    const int n  = gg*HID + jw*JSL + (w & 3)*16 + lr;

    // ---- register-resident weight fragments (B operand), 40 VGPRs ----
    half8 wv[NKK];
    const float bias = bih[n] + bhh[n];
    #pragma unroll
    for (int kk = 0; kk < 2; ++kk) {
        #pragma unroll
        for (int jj = 0; jj < 8; ++jj)
            wv[kk][jj] = (_Float16)Wih[n*NIN + kk*32 + kg*8 + jj];
    }
    #pragma unroll
    for (int kk = 2; kk < NKK; ++kk) {
        #pragma unroll
        for (int jj = 0; jj < 8; ++jj)
            wv[kk][jj] = (_Float16)Whh[n*HID + kk*32 + kg*8 + jj - NIN];
    }

    // ---- init act: h=0, x_0 ----
    for (int i = tid; i < CHUNK*ROWB/4; i += 1024) ((int*)act)[i] = 0;
    __syncthreads();
    {
        float x0 = x[((size_t)(cb + w)*T_SEQ + 0)*NIN + lane];
        *(unsigned short*)(act + w*ROWB + ((lane*2) ^ (w << 4))) = f2h_bits(x0);
    }
    __syncthreads();

    float cst = 0.f;       // cell state for (batch row w, j = jw*64+lane)
    float hlast = 0.f;

    const int pj1 = (jw + 1) & 3, pj2 = (jw + 2) & 3, pj3 = (jw + 3) & 3;

    for (int t = 0; t < T_SEQ; ++t) {
        // prefetch x_{t+1} for row w, col lane (coalesced 256B/wave)
        const int tn = (t+1 < T_SEQ) ? t+1 : T_SEQ-1;
        const float xv = x[((size_t)(cb + w)*T_SEQ + tn)*NIN + lane];

        // A fragments from act (row lr, swizzled)
        half8 af[NKK];
        #pragma unroll
        for (int kk = 0; kk < NKK; ++kk) {
            const int off = (kk*64 + kg*16) ^ (lr << 4);
            af[kk] = *(const half8*)(act + lr*ROWB + off);
        }
        f32x4 acc = {bias, bias, bias, bias};
        #pragma unroll
        for (int kk = 0; kk < NKK; ++kk)
            acc = __builtin_amdgcn_mfma_f32_16x16x32_f16(af[kk], wv[kk], acc, 0, 0, 0);

        // scatter pre-activations: (row kg*4+r, col w*16+lr)
        #pragma unroll
        for (int r = 0; r < 4; ++r)
            gl[kg*4 + r][w*16 + lr] = acc[r];
        __syncthreads();   // B1: gl ready; act safe to overwrite (all af reads done)

        // cell update: this thread owns (row=w, jloc=lane)
        const float iv = sigf(gl[w][          lane]);
        const float fv = sigf(gl[w][  JSL  + lane]);
        const float gv = tanhf_fast(gl[w][2*JSL + lane]);
        const float ov = sigf(gl[w][3*JSL + lane]);
        const float cc = fv*cst + iv*gv;
        cst = cc;
        const float hv = ov*tanhf_fast(cc);
        hlast = hv;
        const unsigned short h16 = f2h_bits(hv);

        // publish IMMEDIATELY (tagged word, relaxed agent atomic -> coherent point)
        const unsigned tgt = (unsigned)(t+1);
        unsigned int* hb = hq + (size_t)((t+1) & 1)*B_TOT*HID + (size_t)(cb + w)*HID;
        __hip_atomic_store(&hb[jw*JSL + lane], (tgt << 16) | (unsigned)h16,
                           __ATOMIC_RELAXED, __HIP_MEMORY_SCOPE_AGENT);

        // own h + x_{t+1} into act while the publish/poll round-trips
        {
            const int mycol = NIN + jw*JSL + lane;
            *(unsigned short*)(act + w*ROWB + ((mycol*2) ^ (w << 4))) = h16;
            if (t < T_SEQ-1)
                *(unsigned short*)(act + w*ROWB + ((lane*2) ^ (w << 4))) = f2h_bits(xv);
        }

        // gather partner h: poll tagged words (3 loads in flight per iteration)
        {
            unsigned v0, v1, v2;
            unsigned int* a0 = &hb[pj1*JSL + lane];
            unsigned int* a1 = &hb[pj2*JSL + lane];
            unsigned int* a2 = &hb[pj3*JSL + lane];
            do {
                v0 = __hip_atomic_load(a0, __ATOMIC_RELAXED, __HIP_MEMORY_SCOPE_AGENT);
                v1 = __hip_atomic_load(a1, __ATOMIC_RELAXED, __HIP_MEMORY_SCOPE_AGENT);
                v2 = __hip_atomic_load(a2, __ATOMIC_RELAXED, __HIP_MEMORY_SCOPE_AGENT);
            } while ((v0 >> 16) != tgt || (v1 >> 16) != tgt || (v2 >> 16) != tgt);
            const int c1 = NIN + pj1*JSL + lane;
            const int c2 = NIN + pj2*JSL + lane;
            const int c3 = NIN + pj3*JSL + lane;
            *(unsigned short*)(act + w*ROWB + ((c1*2) ^ (w << 4))) = (unsigned short)v0;
            *(unsigned short*)(act + w*ROWB + ((c2*2) ^ (w << 4))) = (unsigned short)v1;
            *(unsigned short*)(act + w*ROWB + ((c3*2) ^ (w << 4))) = (unsigned short)v2;
        }

        __syncthreads();   // B2: act ready for next step
    }

    // ---- final FC: partial dot over this WG's 64 j, atomicAdd into out ----
    {
        float v = Wfc[jw*JSL + lane] * hlast;
        if (jw == 0 && lane == 0) v += bfc[0];
        #pragma unroll
        for (int off = 32; off; off >>= 1) v += __shfl_down(v, off);
        if (lane == 0) atomicAdd(&out[cb + w], v);
    }
}

extern "C" void kernel_launch(void* const* d_in, const int* in_sizes, int n_in,
                              void* d_out, int out_size, void* d_ws, size_t ws_size,
                              hipStream_t stream)
{
    const float* x   = (const float*)d_in[0];
    const float* Wih = (const float*)d_in[1];
    const float* Whh = (const float*)d_in[2];
    const float* bih = (const float*)d_in[3];
    const float* bhh = (const float*)d_in[4];
    const float* Wfc = (const float*)d_in[5];
    const float* bfc = (const float*)d_in[6];
    float* out = (float*)d_out;

    unsigned int* hq = (unsigned int*)d_ws;   // [2][256][256] tagged words

    hipMemsetAsync(hq, 0, (size_t)2*B_TOT*HID*sizeof(unsigned int), stream);
    hipMemsetAsync(d_out, 0, out_size*sizeof(float), stream);
    lstm_scan<<<CHUNK*NJW, 1024, 0, stream>>>(x, Wih, Whh, bih, bhh, Wfc, bfc,
                                              out, hq);
}